// Round 4
// baseline (267.923 us; speedup 1.0000x reference)
//
#include <hip/hip_runtime.h>
#include <hip/hip_bf16.h>

#define H 2048
#define LIN 92

typedef __hip_bfloat16 bf16;

// inter-kernel scratch in module device globals; every element fully
// rewritten each call before any read (re-poison safe, graph-capture safe)
__device__ __align__(16) float g_x[96];        // concat input (92 used)
__device__ __align__(16) float g_hs[2][H];     // f32 copies of h_s
__device__ __align__(16) float g_cs[2][H];     // f32 copies of c_s
__device__ __align__(16) float g_p1[4 * H];    // layer-1 recurrent partial + biases
__device__ __align__(16) float g_h0[H];
__device__ __align__(16) float g_h1[H];
__device__ __align__(16) float g_ht[H];
__device__ __align__(16) float g_hid[13 * 64];

__device__ __forceinline__ float b2f(bf16 v) { return __bfloat162float(v); }
__device__ __forceinline__ float sg(float x) { return 1.f / (1.f + __expf(-x)); }

// runtime input-dtype probe: ln_g is all ones in the reference.
// bf16: first u32 = 0x3F803F80 ; f32: 0x3F800000
__device__ __forceinline__ bool is_bf16(const void* ln_g) {
    return *reinterpret_cast<const unsigned*>(ln_g) == 0x3F803F80u;
}

// scalar dtype-agnostic load of element i
__device__ __forceinline__ float ld(const void* p, long i, bool bf) {
    return bf ? b2f(((const bf16*)p)[i]) : ((const float*)p)[i];
}

struct F8 { float v[8]; };

__device__ __forceinline__ F8 load8bf(const bf16* p) {
    uint4 u = *reinterpret_cast<const uint4*>(p);
    F8 r;
    r.v[0] = __uint_as_float(u.x << 16); r.v[1] = __uint_as_float(u.x & 0xffff0000u);
    r.v[2] = __uint_as_float(u.y << 16); r.v[3] = __uint_as_float(u.y & 0xffff0000u);
    r.v[4] = __uint_as_float(u.z << 16); r.v[5] = __uint_as_float(u.z & 0xffff0000u);
    r.v[6] = __uint_as_float(u.w << 16); r.v[7] = __uint_as_float(u.w & 0xffff0000u);
    return r;
}

__device__ __forceinline__ float wred(float x) {
    #pragma unroll
    for (int o = 32; o > 0; o >>= 1) x += __shfl_down(x, o);
    return x;
}

// dot of weight row (element offset rowoff, length 2048, dtype per bf)
// with f32 vector vec; per-wave, lane in [0,64)
__device__ __forceinline__ float dotw(const void* W, long rowoff, const float* vec,
                                      int lane, bool bf) {
    float acc = 0.f;
    if (bf) {
        const bf16* r = (const bf16*)W + rowoff;
        #pragma unroll
        for (int i = 0; i < 4; i++) {
            int col = i * 512 + lane * 8;
            F8 a = load8bf(r + col);
            const float4* hp = reinterpret_cast<const float4*>(vec + col);
            float4 h0 = hp[0], h1 = hp[1];
            acc = fmaf(a.v[0], h0.x, acc); acc = fmaf(a.v[1], h0.y, acc);
            acc = fmaf(a.v[2], h0.z, acc); acc = fmaf(a.v[3], h0.w, acc);
            acc = fmaf(a.v[4], h1.x, acc); acc = fmaf(a.v[5], h1.y, acc);
            acc = fmaf(a.v[6], h1.z, acc); acc = fmaf(a.v[7], h1.w, acc);
        }
    } else {
        const float* r = (const float*)W + rowoff;
        #pragma unroll
        for (int i = 0; i < 4; i++) {
            int col = i * 512 + lane * 8;
            const float4* ap = reinterpret_cast<const float4*>(r + col);
            const float4* hp = reinterpret_cast<const float4*>(vec + col);
            float4 a0 = ap[0], a1 = ap[1];
            float4 h0 = hp[0], h1 = hp[1];
            acc = fmaf(a0.x, h0.x, acc); acc = fmaf(a0.y, h0.y, acc);
            acc = fmaf(a0.z, h0.z, acc); acc = fmaf(a0.w, h0.w, acc);
            acc = fmaf(a1.x, h1.x, acc); acc = fmaf(a1.y, h1.y, acc);
            acc = fmaf(a1.z, h1.z, acc); acc = fmaf(a1.w, h1.w, acc);
        }
    }
    return acc;
}

// stage activations to f32 scratch (dtype-agnostic)
__global__ __launch_bounds__(256) void k_prep(
    const void* __restrict__ lap, const int* __restrict__ idx,
    const void* __restrict__ h_s, const void* __restrict__ c_s,
    const void* __restrict__ e_team, const void* __restrict__ e_trk,
    const void* __restrict__ e_drv, const void* __restrict__ e_cmp,
    const void* __restrict__ ln_g)
{
    bool bf = is_bf16(ln_g);
    int tid = threadIdx.x;
    for (int i = tid; i < H; i += 256) {
        g_hs[0][i] = ld(h_s, i, bf);
        g_hs[1][i] = ld(h_s, H + i, bf);
        g_cs[0][i] = ld(c_s, i, bf);
        g_cs[1][i] = ld(c_s, H + i, bf);
    }
    if (tid < LIN) {
        float v;
        if (tid < 60)      v = ld(lap, tid, bf);
        else if (tid < 68) v = ld(e_team, idx[3] * 8 + tid - 60, bf);
        else if (tid < 76) v = ld(e_trk,  idx[2] * 8 + tid - 68, bf);
        else if (tid < 84) v = ld(e_drv,  idx[1] * 8 + tid - 76, bf);
        else               v = ld(e_cmp,  idx[0] * 8 + tid - 84, bf);
        g_x[tid] = v;
    }
}

// blocks 0..2047: full LSTM layer-0 cell for element j
// blocks 2048..4095: g_p1[row] = W_hh1[row]·h_s[1] + b_ih1 + b_hh1
__global__ __launch_bounds__(256) void k_phaseA(
    const void* __restrict__ Wih0, const void* __restrict__ Whh0,
    const void* __restrict__ bih0, const void* __restrict__ bhh0,
    const void* __restrict__ Whh1, const void* __restrict__ bih1,
    const void* __restrict__ bhh1, const void* __restrict__ ln_g,
    float* __restrict__ out)
{
    bool bf = is_bf16(ln_g);
    int tid = threadIdx.x, w = tid >> 6, lane = tid & 63;
    if (blockIdx.x < H) {
        int j = blockIdx.x;
        __shared__ float gsh[4];
        long row = j + (long)w * H;
        float acc = 0.f;
        if (lane < 46) {  // 92-wide input dot, 2 cols per lane
            long o = row * LIN + lane * 2;
            acc = g_x[lane * 2] * ld(Wih0, o, bf) + g_x[lane * 2 + 1] * ld(Wih0, o + 1, bf);
        }
        acc += dotw(Whh0, row * H, g_hs[0], lane, bf);
        acc = wred(acc);
        if (lane == 0) gsh[w] = acc + ld(bih0, row, bf) + ld(bhh0, row, bf);
        __syncthreads();
        if (tid == 0) {
            float gi = gsh[0], gf = gsh[1], gg = gsh[2], go = gsh[3];
            float cp = g_cs[0][j];
            float cn = sg(gf) * cp + sg(gi) * tanhf(gg);
            float hn = sg(go) * tanhf(cn);
            out[j]         = hn;   // new_h[0]
            out[2 * H + j] = cn;   // new_c[0]
            g_h0[j] = hn;
        }
    } else {
        long row = (long)(blockIdx.x - H) * 4 + w;
        float acc = dotw(Whh1, row * H, g_hs[1], lane, bf);
        acc = wred(acc);
        if (lane == 0) g_p1[row] = acc + ld(bih1, row, bf) + ld(bhh1, row, bf);
    }
}

__global__ __launch_bounds__(256) void k_lstm1(
    const void* __restrict__ Wih1, const void* __restrict__ ln_g,
    float* __restrict__ out)
{
    bool bf = is_bf16(ln_g);
    int tid = threadIdx.x, w = tid >> 6, lane = tid & 63;
    int j = blockIdx.x;
    long row = j + (long)w * H;
    float acc = dotw(Wih1, row * H, g_h0, lane, bf);
    acc = wred(acc);
    __shared__ float gsh[4];
    if (lane == 0) gsh[w] = acc + g_p1[row];
    __syncthreads();
    if (tid == 0) {
        float gi = gsh[0], gf = gsh[1], gg = gsh[2], go = gsh[3];
        float cp = g_cs[1][j];
        float cn = sg(gf) * cp + sg(gi) * tanhf(gg);
        float hn = sg(go) * tanhf(cn);
        out[H + j]     = hn;   // new_h[1]
        out[3 * H + j] = cn;   // new_c[1]
        g_h1[j] = hn;
    }
}

__global__ __launch_bounds__(256) void k_ln(
    const void* __restrict__ g, const void* __restrict__ b)
{
    bool bf = is_bf16(g);
    int tid = threadIdx.x, w = tid >> 6, lane = tid & 63;
    float vals[8];
    float s = 0.f, s2 = 0.f;
    #pragma unroll
    for (int i = 0; i < 8; i++) {
        float v = g_h1[tid + i * 256];
        vals[i] = v; s += v; s2 += v * v;
    }
    s = wred(s); s2 = wred(s2);
    __shared__ float sh[8];
    __shared__ float mv[2];
    if (lane == 0) { sh[w] = s; sh[4 + w] = s2; }
    __syncthreads();
    if (tid == 0) {
        float ts = sh[0] + sh[1] + sh[2] + sh[3];
        float t2 = sh[4] + sh[5] + sh[6] + sh[7];
        float mu = ts / (float)H;
        float var = t2 / (float)H - mu * mu;
        mv[0] = mu; mv[1] = rsqrtf(var + 1e-5f);
    }
    __syncthreads();
    float mu = mv[0], rs = mv[1];
    #pragma unroll
    for (int i = 0; i < 8; i++) {
        int e = tid + i * 256;
        g_ht[e] = (vals[i] - mu) * rs * ld(g, e, bf) + ld(b, e, bf);
    }
}

// head hidden: 13 heads x 64 units, one unit per wave
__global__ __launch_bounds__(256) void k_head1(
    const void* __restrict__ W1, const void* __restrict__ b1,
    const void* __restrict__ ln_g)
{
    bool bf = is_bf16(ln_g);
    int tid = threadIdx.x, w = tid >> 6, lane = tid & 63;
    int k = blockIdx.x >> 4, o = (blockIdx.x & 15) * 4 + w;
    float acc = dotw(W1, ((long)k * 64 + o) * H, g_ht, lane, bf);
    acc = wred(acc);
    if (lane == 0) {
        float v = acc + ld(b1, k * 64 + o, bf);
        g_hid[k * 64 + o] = v > 0.f ? v : 0.f;
    }
}

__global__ __launch_bounds__(128) void k_head2(
    const void* __restrict__ W2, const void* __restrict__ b2,
    const void* __restrict__ ln_g, float* __restrict__ out)
{
    const int HO[13]  = {5,1,1,1,1,1,1,1,9,1,3,1,1};
    const int OFF[13] = {0,5,6,7,8,9,10,11,12,21,22,25,26};
    bool bf = is_bf16(ln_g);
    int t = threadIdx.x;
    if (t >= 117) return;
    int k = t / 9, p = t % 9;
    if (p >= HO[k]) return;
    long wbase = ((long)k * 9 + p) * 64;
    const float* hp = g_hid + k * 64;
    float acc = ld(b2, k * 9 + p, bf);
    #pragma unroll
    for (int o = 0; o < 64; o++) acc = fmaf(hp[o], ld(W2, wbase + o, bf), acc);
    out[4 * H + OFF[k] + p] = acc;
}

extern "C" void kernel_launch(void* const* d_in, const int* in_sizes, int n_in,
                              void* d_out, int out_size, void* d_ws, size_t ws_size,
                              hipStream_t stream) {
    const void* lap    = d_in[0];
    const int*  idx    = (const int*)d_in[1];
    const void* h_s    = d_in[2];
    const void* c_s    = d_in[3];
    const void* e_team = d_in[4];
    const void* e_trk  = d_in[5];
    const void* e_drv  = d_in[6];
    const void* e_cmp  = d_in[7];
    const void* Wih0   = d_in[8];
    const void* Whh0   = d_in[9];
    const void* bih0   = d_in[10];
    const void* bhh0   = d_in[11];
    const void* Wih1   = d_in[12];
    const void* Whh1   = d_in[13];
    const void* bih1   = d_in[14];
    const void* bhh1   = d_in[15];
    const void* ln_g   = d_in[16];
    const void* ln_b   = d_in[17];
    const void* hW1    = d_in[18];
    const void* hb1    = d_in[19];
    const void* hW2    = d_in[20];
    const void* hb2    = d_in[21];
    float* out = (float*)d_out;

    k_prep<<<1, 256, 0, stream>>>(lap, idx, h_s, c_s, e_team, e_trk, e_drv, e_cmp, ln_g);
    k_phaseA<<<4096, 256, 0, stream>>>(Wih0, Whh0, bih0, bhh0, Whh1, bih1, bhh1, ln_g, out);
    k_lstm1<<<2048, 256, 0, stream>>>(Wih1, ln_g, out);
    k_ln<<<1, 256, 0, stream>>>(ln_g, ln_b);
    k_head1<<<208, 256, 0, stream>>>(hW1, hb1, ln_g);
    k_head2<<<1, 128, 0, stream>>>(hW2, hb2, ln_g, out);
}

// Round 5
// 249.790 us; speedup vs baseline: 1.0726x; 1.0726x over previous
//
#include <hip/hip_runtime.h>

#define H 2048

// inter-kernel scratch (device globals; fully rewritten every call before read)
__device__ __align__(16) float g_p1[4 * H];   // layer-1 recurrent partial + both biases
__device__ __align__(16) float g_h0[H];       // layer-0 new h
__device__ __align__(16) float g_h1[H];       // layer-1 new h
__device__ __align__(16) float g_hid[13 * 64];// head hidden activations

__device__ __forceinline__ float sg(float x) { return 1.f / (1.f + __expf(-x)); }

__device__ __forceinline__ float wred(float x) {
    #pragma unroll
    for (int o = 32; o > 0; o >>= 1) x += __shfl_down(x, o);
    return x;
}

// per-wave dot: global f32 row (2048) · LDS f32 vec (2048); lane in [0,64)
// 8 x float4 per lane, each load instr covers 1KB contiguous
__device__ __forceinline__ float dotg(const float* __restrict__ row,
                                      const float* __restrict__ vec, int lane) {
    float acc = 0.f;
    #pragma unroll
    for (int i = 0; i < 8; i++) {
        int c = i * 256 + lane * 4;
        float4 a = *reinterpret_cast<const float4*>(row + c);
        float4 v = *reinterpret_cast<const float4*>(vec + c);
        acc = fmaf(a.x, v.x, acc); acc = fmaf(a.y, v.y, acc);
        acc = fmaf(a.z, v.z, acc); acc = fmaf(a.w, v.w, acc);
    }
    return acc;
}

// K1: blocks 0..511   -> layer-0 LSTM cells (4 cells/block, 1 cell/wave: all 4 gates)
//     blocks 512..1023-> W_hh1 recurrent partials (16 rows/block, 4 rows/wave)
__global__ __launch_bounds__(256) void k1(
    const float* __restrict__ lap, const int* __restrict__ idx,
    const float* __restrict__ h_s, const float* __restrict__ c_s,
    const float* __restrict__ e_team, const float* __restrict__ e_trk,
    const float* __restrict__ e_drv, const float* __restrict__ e_cmp,
    const float* __restrict__ Wih0, const float* __restrict__ Whh0,
    const float* __restrict__ bih0, const float* __restrict__ bhh0,
    const float* __restrict__ Whh1, const float* __restrict__ bih1,
    const float* __restrict__ bhh1, float* __restrict__ out)
{
    __shared__ float vec[H];
    __shared__ float xsh[96];
    int tid = threadIdx.x, w = tid >> 6, lane = tid & 63;
    int b = blockIdx.x;
    bool l0 = b < 512;
    const float* src = l0 ? h_s : (h_s + H);
    #pragma unroll
    for (int i = 0; i < 8; i++) vec[tid + i * 256] = src[tid + i * 256];
    if (l0 && tid < 92) {
        float v;
        if (tid < 60)      v = lap[tid];
        else if (tid < 68) v = e_team[idx[3] * 8 + tid - 60];
        else if (tid < 76) v = e_trk [idx[2] * 8 + tid - 68];
        else if (tid < 84) v = e_drv [idx[1] * 8 + tid - 76];
        else               v = e_cmp [idx[0] * 8 + tid - 84];
        xsh[tid] = v;
    }
    __syncthreads();

    if (l0) {
        int j = b * 4 + w;              // this wave's cell
        float acc[4];
        #pragma unroll
        for (int g = 0; g < 4; g++) {
            long row = j + (long)g * H;
            float a = dotg(Whh0 + row * H, vec, lane);
            const float* wr = Wih0 + row * 92;   // 92-wide input dot
            float p = xsh[lane] * wr[lane];
            if (lane < 28) p += xsh[lane + 64] * wr[lane + 64];
            acc[g] = a + p;
        }
        #pragma unroll
        for (int g = 0; g < 4; g++) acc[g] = wred(acc[g]);
        if (lane == 0) {
            float gi = acc[0] + bih0[j]         + bhh0[j];
            float gf = acc[1] + bih0[j + H]     + bhh0[j + H];
            float gg = acc[2] + bih0[j + 2 * H] + bhh0[j + 2 * H];
            float go = acc[3] + bih0[j + 3 * H] + bhh0[j + 3 * H];
            float cp = c_s[j];
            float cn = sg(gf) * cp + sg(gi) * tanhf(gg);
            float hn = sg(go) * tanhf(cn);
            out[j]         = hn;   // new_h[0]
            out[2 * H + j] = cn;   // new_c[0]
            g_h0[j] = hn;
        }
    } else {
        int rb = (b - 512) * 16 + w * 4;   // 4 rows per wave
        float acc[4];
        #pragma unroll
        for (int r = 0; r < 4; r++) acc[r] = dotg(Whh1 + (long)(rb + r) * H, vec, lane);
        #pragma unroll
        for (int r = 0; r < 4; r++) acc[r] = wred(acc[r]);
        if (lane == 0) {
            #pragma unroll
            for (int r = 0; r < 4; r++) g_p1[rb + r] = acc[r] + bih1[rb + r] + bhh1[rb + r];
        }
    }
}

// K2: layer-1 LSTM cells. 4 cells/block, 1 cell/wave.
__global__ __launch_bounds__(256) void k2(
    const float* __restrict__ Wih1, const float* __restrict__ c_s,
    float* __restrict__ out)
{
    __shared__ float vec[H];
    int tid = threadIdx.x, w = tid >> 6, lane = tid & 63;
    #pragma unroll
    for (int i = 0; i < 8; i++) vec[tid + i * 256] = g_h0[tid + i * 256];
    __syncthreads();
    int j = blockIdx.x * 4 + w;
    float acc[4];
    #pragma unroll
    for (int g = 0; g < 4; g++) acc[g] = dotg(Wih1 + (long)(j + g * H) * H, vec, lane);
    #pragma unroll
    for (int g = 0; g < 4; g++) acc[g] = wred(acc[g]);
    if (lane == 0) {
        float gi = acc[0] + g_p1[j];
        float gf = acc[1] + g_p1[j + H];
        float gg = acc[2] + g_p1[j + 2 * H];
        float go = acc[3] + g_p1[j + 3 * H];
        float cp = c_s[H + j];
        float cn = sg(gf) * cp + sg(gi) * tanhf(gg);
        float hn = sg(go) * tanhf(cn);
        out[H + j]     = hn;   // new_h[1]
        out[3 * H + j] = cn;   // new_c[1]
        g_h1[j] = hn;
    }
}

// K3: fused LayerNorm (redundant per block) + head hidden layer.
// grid = 104 blocks: head k = b>>3, units (b&7)*8 .. +7; 2 units per wave.
__global__ __launch_bounds__(256) void k3(
    const float* __restrict__ ln_g, const float* __restrict__ ln_b,
    const float* __restrict__ W1, const float* __restrict__ b1)
{
    __shared__ float ht[H];
    __shared__ float red[8];
    __shared__ float mvs[2];
    int tid = threadIdx.x, w = tid >> 6, lane = tid & 63;
    float v[8];
    float s = 0.f, s2 = 0.f;
    #pragma unroll
    for (int i = 0; i < 8; i++) {
        float x = g_h1[tid + i * 256];
        v[i] = x; s += x; s2 += x * x;
    }
    s = wred(s); s2 = wred(s2);
    if (lane == 0) { red[w] = s; red[4 + w] = s2; }
    __syncthreads();
    if (tid == 0) {
        float ts = red[0] + red[1] + red[2] + red[3];
        float t2 = red[4] + red[5] + red[6] + red[7];
        float mu = ts / (float)H;
        float var = t2 / (float)H - mu * mu;
        mvs[0] = mu; mvs[1] = rsqrtf(var + 1e-5f);
    }
    __syncthreads();
    float mu = mvs[0], rs = mvs[1];
    #pragma unroll
    for (int i = 0; i < 8; i++) {
        int e = tid + i * 256;
        ht[e] = (v[i] - mu) * rs * ln_g[e] + ln_b[e];
    }
    __syncthreads();
    int k  = blockIdx.x >> 3;
    int u0 = (blockIdx.x & 7) * 8 + w * 2;
    #pragma unroll
    for (int u = 0; u < 2; u++) {
        int o = u0 + u;
        float acc = dotg(W1 + ((long)k * 64 + o) * H, ht, lane);
        acc = wred(acc);
        if (lane == 0) {
            float r = acc + b1[k * 64 + o];
            g_hid[k * 64 + o] = r > 0.f ? r : 0.f;
        }
    }
}

// K4: head output layer (tiny)
__global__ __launch_bounds__(128) void k4(
    const float* __restrict__ W2, const float* __restrict__ b2,
    float* __restrict__ out)
{
    const int HO[13]  = {5,1,1,1,1,1,1,1,9,1,3,1,1};
    const int OFF[13] = {0,5,6,7,8,9,10,11,12,21,22,25,26};
    int t = threadIdx.x;
    if (t >= 117) return;
    int k = t / 9, p = t % 9;
    if (p >= HO[k]) return;
    const float* wr = W2 + ((long)k * 9 + p) * 64;
    const float* hp = g_hid + k * 64;
    float acc = b2[k * 9 + p];
    #pragma unroll
    for (int o = 0; o < 64; o++) acc = fmaf(hp[o], wr[o], acc);
    out[4 * H + OFF[k] + p] = acc;
}

extern "C" void kernel_launch(void* const* d_in, const int* in_sizes, int n_in,
                              void* d_out, int out_size, void* d_ws, size_t ws_size,
                              hipStream_t stream) {
    const float* lap    = (const float*)d_in[0];
    const int*   idx    = (const int*)  d_in[1];
    const float* h_s    = (const float*)d_in[2];
    const float* c_s    = (const float*)d_in[3];
    const float* e_team = (const float*)d_in[4];
    const float* e_trk  = (const float*)d_in[5];
    const float* e_drv  = (const float*)d_in[6];
    const float* e_cmp  = (const float*)d_in[7];
    const float* Wih0   = (const float*)d_in[8];
    const float* Whh0   = (const float*)d_in[9];
    const float* bih0   = (const float*)d_in[10];
    const float* bhh0   = (const float*)d_in[11];
    const float* Wih1   = (const float*)d_in[12];
    const float* Whh1   = (const float*)d_in[13];
    const float* bih1   = (const float*)d_in[14];
    const float* bhh1   = (const float*)d_in[15];
    const float* ln_g   = (const float*)d_in[16];
    const float* ln_b   = (const float*)d_in[17];
    const float* hW1    = (const float*)d_in[18];
    const float* hb1    = (const float*)d_in[19];
    const float* hW2    = (const float*)d_in[20];
    const float* hb2    = (const float*)d_in[21];
    float* out = (float*)d_out;

    k1<<<1024, 256, 0, stream>>>(lap, idx, h_s, c_s, e_team, e_trk, e_drv, e_cmp,
                                 Wih0, Whh0, bih0, bhh0, Whh1, bih1, bhh1, out);
    k2<<<512, 256, 0, stream>>>(Wih1, c_s, out);
    k3<<<104, 256, 0, stream>>>(ln_g, ln_b, hW1, hb1);
    k4<<<1, 128, 0, stream>>>(hW2, hb2, out);
}

// Round 6
// 247.856 us; speedup vs baseline: 1.0810x; 1.0078x over previous
//
#include <hip/hip_runtime.h>

#define H 2048

// inter-kernel scratch (device globals; fully rewritten every call before read)
__device__ __align__(16) float g_p1[4 * H];   // layer-1 recurrent partial + both biases
__device__ __align__(16) float g_h0[H];       // layer-0 new h
__device__ __align__(16) float g_h1[H];       // layer-1 new h
__device__ __align__(16) float g_hid[13 * 64];// head hidden activations

__device__ __forceinline__ float sg(float x) { return 1.f / (1.f + __expf(-x)); }

__device__ __forceinline__ float wred(float x) {
    #pragma unroll
    for (int o = 32; o > 0; o >>= 1) x += __shfl_down(x, o);
    return x;
}

// per-wave row dot: issue ALL 8 global float4 loads back-to-back (8 KB/wave in
// flight), then fma against LDS vec. 32 payload VGPRs; maximizes MLP.
__device__ __forceinline__ float dotrow(const float* __restrict__ row,
                                        const float* __restrict__ vecLDS, int lane) {
    float4 a[8];
    #pragma unroll
    for (int i = 0; i < 8; i++)
        a[i] = *reinterpret_cast<const float4*>(row + i * 256 + lane * 4);
    float acc = 0.f;
    #pragma unroll
    for (int i = 0; i < 8; i++) {
        float4 v = *reinterpret_cast<const float4*>(vecLDS + i * 256 + lane * 4);
        acc = fmaf(a[i].x, v.x, acc); acc = fmaf(a[i].y, v.y, acc);
        acc = fmaf(a[i].z, v.z, acc); acc = fmaf(a[i].w, v.w, acc);
    }
    return acc;
}

// K1: blocks 0..2047   -> layer-0 LSTM cell j=b; wave w = gate row j + w*H
//     blocks 2048..4095-> Whh1 recurrent partials, 1 row/wave
__global__ __launch_bounds__(256) void k1(
    const float* __restrict__ lap, const int* __restrict__ idx,
    const float* __restrict__ h_s, const float* __restrict__ c_s,
    const float* __restrict__ e_team, const float* __restrict__ e_trk,
    const float* __restrict__ e_drv, const float* __restrict__ e_cmp,
    const float* __restrict__ Wih0, const float* __restrict__ Whh0,
    const float* __restrict__ bih0, const float* __restrict__ bhh0,
    const float* __restrict__ Whh1, const float* __restrict__ bih1,
    const float* __restrict__ bhh1, float* __restrict__ out)
{
    __shared__ float vec[H];
    __shared__ float xsh[96];
    __shared__ float gsh[4];
    int tid = threadIdx.x, w = tid >> 6, lane = tid & 63;
    int b = blockIdx.x;
    bool l0 = b < 2048;
    const float* src = l0 ? h_s : (h_s + H);
    #pragma unroll
    for (int i = 0; i < 8; i++) vec[tid + i * 256] = src[tid + i * 256];
    if (l0 && tid < 92) {
        float v;
        if (tid < 60)      v = lap[tid];
        else if (tid < 68) v = e_team[idx[3] * 8 + tid - 60];
        else if (tid < 76) v = e_trk [idx[2] * 8 + tid - 68];
        else if (tid < 84) v = e_drv [idx[1] * 8 + tid - 76];
        else               v = e_cmp [idx[0] * 8 + tid - 84];
        xsh[tid] = v;
    }
    __syncthreads();

    if (l0) {
        int j = b;
        long row = j + (long)w * H;
        float acc = dotrow(Whh0 + row * H, vec, lane);
        const float* wr = Wih0 + row * 92;     // 92-wide input dot
        float p = xsh[lane] * wr[lane];
        if (lane < 28) p += xsh[lane + 64] * wr[lane + 64];
        acc = wred(acc + p);
        if (lane == 0) gsh[w] = acc + bih0[row] + bhh0[row];
        __syncthreads();
        if (tid == 0) {
            float gi = gsh[0], gf = gsh[1], gg = gsh[2], go = gsh[3];
            float cp = c_s[j];
            float cn = sg(gf) * cp + sg(gi) * tanhf(gg);
            float hn = sg(go) * tanhf(cn);
            out[j]         = hn;   // new_h[0]
            out[2 * H + j] = cn;   // new_c[0]
            g_h0[j] = hn;
        }
    } else {
        int r = (b - 2048) * 4 + w;            // Whh1 row, 1 per wave
        float acc = dotrow(Whh1 + (long)r * H, vec, lane);
        acc = wred(acc);
        if (lane == 0) g_p1[r] = acc + bih1[r] + bhh1[r];
    }
}

// K2: layer-1 LSTM cell j=b; wave w = gate row j + w*H (1 row/wave, 2048 blocks)
__global__ __launch_bounds__(256) void k2(
    const float* __restrict__ Wih1, const float* __restrict__ c_s,
    float* __restrict__ out)
{
    __shared__ float vec[H];
    __shared__ float gsh[4];
    int tid = threadIdx.x, w = tid >> 6, lane = tid & 63;
    #pragma unroll
    for (int i = 0; i < 8; i++) vec[tid + i * 256] = g_h0[tid + i * 256];
    __syncthreads();
    int j = blockIdx.x;
    long row = j + (long)w * H;
    float acc = dotrow(Wih1 + row * H, vec, lane);
    acc = wred(acc);
    if (lane == 0) gsh[w] = acc + g_p1[row];
    __syncthreads();
    if (tid == 0) {
        float gi = gsh[0], gf = gsh[1], gg = gsh[2], go = gsh[3];
        float cp = c_s[H + j];
        float cn = sg(gf) * cp + sg(gi) * tanhf(gg);
        float hn = sg(go) * tanhf(cn);
        out[H + j]     = hn;   // new_h[1]
        out[3 * H + j] = cn;   // new_c[1]
        g_h1[j] = hn;
    }
}

// K3: fused LayerNorm (redundant per block) + head hidden. 208 blocks:
// head k = b>>4, unit o = (b&15)*4 + wave (1 unit/wave).
__global__ __launch_bounds__(256) void k3(
    const float* __restrict__ ln_g, const float* __restrict__ ln_b,
    const float* __restrict__ W1, const float* __restrict__ b1)
{
    __shared__ float ht[H];
    __shared__ float red[8];
    __shared__ float mvs[2];
    int tid = threadIdx.x, w = tid >> 6, lane = tid & 63;
    float v[8];
    float s = 0.f, s2 = 0.f;
    #pragma unroll
    for (int i = 0; i < 8; i++) {
        float x = g_h1[tid + i * 256];
        v[i] = x; s += x; s2 += x * x;
    }
    s = wred(s); s2 = wred(s2);
    if (lane == 0) { red[w] = s; red[4 + w] = s2; }
    __syncthreads();
    if (tid == 0) {
        float ts = red[0] + red[1] + red[2] + red[3];
        float t2 = red[4] + red[5] + red[6] + red[7];
        float mu = ts / (float)H;
        float var = t2 / (float)H - mu * mu;
        mvs[0] = mu; mvs[1] = rsqrtf(var + 1e-5f);
    }
    __syncthreads();
    float mu = mvs[0], rs = mvs[1];
    #pragma unroll
    for (int i = 0; i < 8; i++) {
        int e = tid + i * 256;
        ht[e] = (v[i] - mu) * rs * ln_g[e] + ln_b[e];
    }
    __syncthreads();
    int k = blockIdx.x >> 4;
    int o = (blockIdx.x & 15) * 4 + w;
    float acc = dotrow(W1 + ((long)k * 64 + o) * H, ht, lane);
    acc = wred(acc);
    if (lane == 0) {
        float r = acc + b1[k * 64 + o];
        g_hid[k * 64 + o] = r > 0.f ? r : 0.f;
    }
}

// K4: head output layer (tiny)
__global__ __launch_bounds__(128) void k4(
    const float* __restrict__ W2, const float* __restrict__ b2,
    float* __restrict__ out)
{
    const int HO[13]  = {5,1,1,1,1,1,1,1,9,1,3,1,1};
    const int OFF[13] = {0,5,6,7,8,9,10,11,12,21,22,25,26};
    int t = threadIdx.x;
    if (t >= 117) return;
    int k = t / 9, p = t % 9;
    if (p >= HO[k]) return;
    const float* wr = W2 + ((long)k * 9 + p) * 64;
    const float* hp = g_hid + k * 64;
    float acc = b2[k * 9 + p];
    #pragma unroll
    for (int o = 0; o < 64; o++) acc = fmaf(hp[o], wr[o], acc);
    out[4 * H + OFF[k] + p] = acc;
}

extern "C" void kernel_launch(void* const* d_in, const int* in_sizes, int n_in,
                              void* d_out, int out_size, void* d_ws, size_t ws_size,
                              hipStream_t stream) {
    const float* lap    = (const float*)d_in[0];
    const int*   idx    = (const int*)  d_in[1];
    const float* h_s    = (const float*)d_in[2];
    const float* c_s    = (const float*)d_in[3];
    const float* e_team = (const float*)d_in[4];
    const float* e_trk  = (const float*)d_in[5];
    const float* e_drv  = (const float*)d_in[6];
    const float* e_cmp  = (const float*)d_in[7];
    const float* Wih0   = (const float*)d_in[8];
    const float* Whh0   = (const float*)d_in[9];
    const float* bih0   = (const float*)d_in[10];
    const float* bhh0   = (const float*)d_in[11];
    const float* Wih1   = (const float*)d_in[12];
    const float* Whh1   = (const float*)d_in[13];
    const float* bih1   = (const float*)d_in[14];
    const float* bhh1   = (const float*)d_in[15];
    const float* ln_g   = (const float*)d_in[16];
    const float* ln_b   = (const float*)d_in[17];
    const float* hW1    = (const float*)d_in[18];
    const float* hb1    = (const float*)d_in[19];
    const float* hW2    = (const float*)d_in[20];
    const float* hb2    = (const float*)d_in[21];
    float* out = (float*)d_out;

    k1<<<4096, 256, 0, stream>>>(lap, idx, h_s, c_s, e_team, e_trk, e_drv, e_cmp,
                                 Wih0, Whh0, bih0, bhh0, Whh1, bih1, bhh1, out);
    k2<<<2048, 256, 0, stream>>>(Wih1, c_s, out);
    k3<<<208, 256, 0, stream>>>(ln_g, ln_b, hW1, hb1);
    k4<<<1, 128, 0, stream>>>(hW2, hb2, out);
}